// Round 7
// baseline (437.830 us; speedup 1.0000x reference)
//
#include <hip/hip_runtime.h>

#define EMB 16
#define BSH 7                 // 128 right-nodes per bucket
#define BNODES 128
#define MAXNB 1024
#define PCHUNK 16384
#define STRD 17               // padded LDS row stride (bank-conflict break)
typedef unsigned int u32;
typedef unsigned long long u64;

__global__ void zero_f32(float* __restrict__ p, size_t n) {
    size_t i = (size_t)blockIdx.x * blockDim.x + threadIdx.x;
    size_t stride = (size_t)gridDim.x * blockDim.x;
    for (; i < n; i += stride) p[i] = 0.0f;
}

__global__ void zero_i32(int* __restrict__ p, int n) {
    int i = blockIdx.x * blockDim.x + threadIdx.x;
    if (i < n) p[i] = 0;
}

__device__ __forceinline__ u32 bf16bits_rne(float x) {
    u32 u = __float_as_uint(x);
    return (u + 0x7fffu + ((u >> 16) & 1u)) >> 16;
}

// Packed bf16 linear: Y[row*8+h] = pack(bf16(row@W[:,h+8]+b), bf16(row@W[:,h]+b))
__global__ void linear16_pack_kernel(const float* __restrict__ X, const float* __restrict__ W,
                                     const float* __restrict__ b, u32* __restrict__ Y, int N) {
    int tid = blockIdx.x * blockDim.x + threadIdx.x;
    int row = tid >> 3;
    int h = tid & 7;
    if (row >= N) return;
    float a0 = b ? b[h] : 0.0f;
    float a1 = b ? b[h + 8] : 0.0f;
    const float* xr = X + (size_t)row * EMB;
#pragma unroll
    for (int k = 0; k < EMB; ++k) {
        float xv = xr[k];
        a0 = fmaf(xv, W[k * EMB + h], a0);
        a1 = fmaf(xv, W[k * EMB + h + 8], a1);
    }
    Y[(size_t)row * 8 + h] = (bf16bits_rne(a1) << 16) | bf16bits_rne(a0);
}

// Plain f32 linear (fallback path)
__global__ void linear16_kernel(const float* __restrict__ X, const float* __restrict__ W,
                                const float* __restrict__ b, float* __restrict__ Y, int N) {
    int tid = blockIdx.x * blockDim.x + threadIdx.x;
    int row = tid >> 4;
    int j = tid & 15;
    if (row >= N) return;
    float acc = b ? b[j] : 0.0f;
    const float* xr = X + (size_t)row * EMB;
#pragma unroll
    for (int k = 0; k < EMB; ++k) acc = fmaf(xr[k], W[k * EMB + j], acc);
    Y[(size_t)row * EMB + j] = acc;
}

// ---------------- bucket CSR build ----------------

__global__ void bucket_hist_kernel(const int* __restrict__ ridx, int* __restrict__ bhist,
                                   int E, int NB) {
    __shared__ int h[MAXNB];
    int t = threadIdx.x;
    for (int i = t; i < NB; i += 256) h[i] = 0;
    __syncthreads();
    int idx = blockIdx.x * blockDim.x + t;
    int stride = gridDim.x * blockDim.x;
    for (int e = idx; e < E; e += stride) atomicAdd(&h[ridx[e] >> BSH], 1);
    __syncthreads();
    for (int i = t; i < NB; i += 256) if (h[i]) atomicAdd(&bhist[i], h[i]);
}

__global__ void bucket_scan_kernel(const int* __restrict__ bhist, int* __restrict__ boff,
                                   int* __restrict__ gcur, int NB) {
    __shared__ int sc[1024];
    int t = threadIdx.x;
    int v = (t < NB) ? bhist[t] : 0;
    sc[t] = v;
    __syncthreads();
    for (int d = 1; d < 1024; d <<= 1) {
        int x = (t >= d) ? sc[t - d] : 0;
        __syncthreads();
        sc[t] += x;
        __syncthreads();
    }
    int excl = sc[t] - v;
    if (t < NB) { boff[t] = excl; gcur[t] = excl; }
    if (t == 1023) boff[NB] = sc[1023];
}

// Two-pass partition: LDS hist -> one aggregated global reservation per bucket
// -> clustered scatter of packed records [f:32][l:24][rl:7].
__launch_bounds__(512)
__global__ void partition_kernel(const int* __restrict__ eidx, const float* __restrict__ ef,
                                 int* __restrict__ gcur, u64* __restrict__ rec, int E, int NB) {
    __shared__ int hist[MAXNB];
    __shared__ int lbase[MAXNB];
    int t = threadIdx.x;
    long long base = (long long)blockIdx.x * PCHUNK;
    int n = (int)((E - base) < PCHUNK ? (E - base) : PCHUNK);
    const int* ridx = eidx + E;
    for (int i = t; i < NB; i += 512) hist[i] = 0;
    __syncthreads();
    for (int i = t; i < n; i += 512) atomicAdd(&hist[ridx[base + i] >> BSH], 1);
    __syncthreads();
    for (int i = t; i < NB; i += 512) {
        int h = hist[i];
        lbase[i] = h ? atomicAdd(&gcur[i], h) : 0;
        hist[i] = 0;  // reuse as local cursor
    }
    __syncthreads();
    for (int i = t; i < n; i += 512) {
        int r = ridx[base + i];
        int b = r >> BSH;
        int l = eidx[base + i];
        float f = ef[base + i];
        int pos = lbase[b] + atomicAdd(&hist[b], 1);
        rec[pos] = ((u64)__float_as_uint(f) << 32) | ((u64)(u32)l << BSH) | (u32)(r & (BNODES - 1));
    }
}

// ---------------- gather: one block per 128-node bucket ----------------
// One THREAD per edge (whole 16-comp row), batches of 4 edges per thread so
// wide independent loads stay in flight; native LDS fp atomics for accumulate.
__launch_bounds__(512)
__global__ void bucket_gather_kernel(const u64* __restrict__ rec, const int* __restrict__ boff,
                                     const u32* __restrict__ Lpk, const u32* __restrict__ Rpk,
                                     const float* __restrict__ We,
                                     float* __restrict__ S, int* __restrict__ deg, int n_right) {
    __shared__ float Stile[BNODES * STRD];          // 8.7 KB
    __shared__ __align__(16) u32 Rt[BNODES * 8];    // 4 KB packed bf16 R rows
    __shared__ int dtile[BNODES];
    int b = blockIdx.x;
    int t = threadIdx.x;
    int node0 = b << BSH;
    int nn = n_right - node0; if (nn > BNODES) nn = BNODES;

    for (int i = t; i < BNODES * STRD; i += 512) Stile[i] = 0.0f;
    for (int i = t; i < nn * 8; i += 512) Rt[i] = Rpk[(size_t)node0 * 8 + i];
    for (int i = t; i < BNODES; i += 512) dtile[i] = 0;

    float we[16];
#pragma unroll
    for (int j = 0; j < 16; ++j) we[j] = We[j];  // uniform -> scalar loads

    __syncthreads();

    int start = boff[b], end = boff[b + 1];
    for (int base = start + t; base < end; base += 512 * 4) {
        // ---- batch of up to 4 edges per thread: coalesced rec reads ----
        u64 rc0 = 0, rc1 = 0, rc2 = 0, rc3 = 0;
        bool v0 = base < end;
        bool v1 = base + 512 < end;
        bool v2 = base + 1024 < end;
        bool v3 = base + 1536 < end;
        if (v0) rc0 = rec[base];
        if (v1) rc1 = rec[base + 512];
        if (v2) rc2 = rec[base + 1024];
        if (v3) rc3 = rec[base + 1536];
        // ---- independent wide L-row gathers (8 x dwordx4 in flight) ----
        uint4 la0, lb0, la1, lb1, la2, lb2, la3, lb3;
#define LGATH(v, rc, la, lb) \
        if (v) { const uint4* p = (const uint4*)(Lpk + (size_t)((rc >> BSH) & 0xFFFFFFu) * 8); \
                 la = p[0]; lb = p[1]; }
        LGATH(v0, rc0, la0, lb0)
        LGATH(v1, rc1, la1, lb1)
        LGATH(v2, rc2, la2, lb2)
        LGATH(v3, rc3, la3, lb3)
#undef LGATH
        // ---- compute + LDS accumulate ----
#define EDGE(v, rc, la, lb) \
        if (v) { \
            int rl = (int)(rc & (u32)(BNODES - 1)); \
            float f = __uint_as_float((u32)(rc >> 32)); \
            const uint4* rp = (const uint4*)(Rt + rl * 8); \
            uint4 ra = rp[0], rb = rp[1]; \
            u32 lw0 = la.x, lw1 = la.y, lw2 = la.z, lw3 = la.w; \
            u32 lw4 = lb.x, lw5 = lb.y, lw6 = lb.z, lw7 = lb.w; \
            u32 rw0 = ra.x, rw1 = ra.y, rw2 = ra.z, rw3 = ra.w; \
            u32 rw4 = rb.x, rw5 = rb.y, rw6 = rb.z, rw7 = rb.w; \
            float* srow = &Stile[rl * STRD]; \
            PAIR(0, lw0, rw0) PAIR(1, lw1, rw1) PAIR(2, lw2, rw2) PAIR(3, lw3, rw3) \
            PAIR(4, lw4, rw4) PAIR(5, lw5, rw5) PAIR(6, lw6, rw6) PAIR(7, lw7, rw7) \
            atomicAdd(&dtile[rl], 1); \
        }
#define PAIR(h, lw, rw) { \
            float l0 = __uint_as_float(lw << 16); \
            float l1 = __uint_as_float(lw & 0xffff0000u); \
            float r0 = __uint_as_float(rw << 16); \
            float r1 = __uint_as_float(rw & 0xffff0000u); \
            float q0 = fmaxf(fmaf(f, we[h], l0) + r0, 0.0f); \
            float q1 = fmaxf(fmaf(f, we[h + 8], l1) + r1, 0.0f); \
            unsafeAtomicAdd(srow + h, q0); \
            unsafeAtomicAdd(srow + h + 8, q1); }
        EDGE(v0, rc0, la0, lb0)
        EDGE(v1, rc1, la1, lb1)
        EDGE(v2, rc2, la2, lb2)
        EDGE(v3, rc3, la3, lb3)
#undef EDGE
#undef PAIR
    }
    __syncthreads();
    for (int i = t; i < nn * EMB; i += 512) {
        int node = i >> 4, c = i & 15;
        S[(size_t)(node0 + node) * EMB + c] = Stile[node * STRD + c];
    }
    for (int i = t; i < nn; i += 512) deg[node0 + i] = dtile[i];
}

// ---------------- fallback atomic edge kernel (f32 tables) ----------------
__global__ void edge_kernel(const int* __restrict__ eidx, const float* __restrict__ ef,
                            const float* __restrict__ L, const float* __restrict__ R,
                            const float* __restrict__ We, float* __restrict__ S,
                            int* __restrict__ cnt, int E) {
    long long tid = (long long)blockIdx.x * blockDim.x + threadIdx.x;
    int e = (int)(tid >> 4);
    int j = (int)(tid & 15);
    if (e >= E) return;
    int l = eidx[e];
    int r = eidx[E + e];
    float v = L[(size_t)l * EMB + j] + ef[e] * We[j] + R[(size_t)r * EMB + j];
    v = fmaxf(v, 0.0f);
    unsafeAtomicAdd(&S[(size_t)r * EMB + j], v);
    if (j == 0) atomicAdd(&cnt[r], 1);
}

// ---------------- per-node epilogue ----------------
__global__ void final_kernel(const float* __restrict__ S, const int* __restrict__ deg,
                             const float* __restrict__ rf,
                             const float* __restrict__ Wf, const float* __restrict__ bf,
                             const float* __restrict__ Wp, const float* __restrict__ bp,
                             const float* __restrict__ Wo1, const float* __restrict__ bo1,
                             const float* __restrict__ Wo2, const float* __restrict__ bo2,
                             float* __restrict__ out, int N) {
    __shared__ float sWf[256], sWp[256], sWo1[512], sWo2[256];
    __shared__ float sb[64];
    int t = threadIdx.x;
    for (int i = t; i < 256; i += 256) { sWf[i] = Wf[i]; sWp[i] = Wp[i]; sWo2[i] = Wo2[i]; }
    for (int i = t; i < 512; i += 256) sWo1[i] = Wo1[i];
    if (t < 16) { sb[t] = bf[t]; sb[16 + t] = bp[t]; sb[32 + t] = bo1[t]; sb[48 + t] = bo2[t]; }
    __syncthreads();

    int r = blockIdx.x * blockDim.x + t;
    if (r >= N) return;

    float s[16], x[16], y[16], rv[16], z[16], o[16];
    const float4* Sp = (const float4*)(S + (size_t)r * EMB);
    const float4* Rp = (const float4*)(rf + (size_t)r * EMB);
#pragma unroll
    for (int k = 0; k < 4; ++k) {
        float4 v = Sp[k];
        s[4 * k] = v.x; s[4 * k + 1] = v.y; s[4 * k + 2] = v.z; s[4 * k + 3] = v.w;
        float4 w = Rp[k];
        rv[4 * k] = w.x; rv[4 * k + 1] = w.y; rv[4 * k + 2] = w.z; rv[4 * k + 3] = w.w;
    }
    float c = (float)deg[r];

#pragma unroll
    for (int j = 0; j < 16; ++j) {
        float a = c * sb[j];
#pragma unroll
        for (int k = 0; k < 16; ++k) a = fmaf(s[k], sWf[k * 16 + j], a);
        x[j] = fmaxf(a, 0.0f);
    }
#pragma unroll
    for (int j = 0; j < 16; ++j) {
        float a = sb[16 + j];
#pragma unroll
        for (int k = 0; k < 16; ++k) a = fmaf(x[k], sWp[k * 16 + j], a);
        y[j] = a;
    }
#pragma unroll
    for (int j = 0; j < 16; ++j) {
        float a = sb[32 + j];
#pragma unroll
        for (int k = 0; k < 16; ++k) a = fmaf(y[k], sWo1[k * 16 + j], a);
#pragma unroll
        for (int k = 0; k < 16; ++k) a = fmaf(rv[k], sWo1[(16 + k) * 16 + j], a);
        z[j] = fmaxf(a, 0.0f);
    }
#pragma unroll
    for (int j = 0; j < 16; ++j) {
        float a = sb[48 + j];
#pragma unroll
        for (int k = 0; k < 16; ++k) a = fmaf(z[k], sWo2[k * 16 + j], a);
        o[j] = a;
    }
    float4* Op = (float4*)(out + (size_t)r * EMB);
#pragma unroll
    for (int k = 0; k < 4; ++k)
        Op[k] = make_float4(o[4 * k], o[4 * k + 1], o[4 * k + 2], o[4 * k + 3]);
}

extern "C" void kernel_launch(void* const* d_in, const int* in_sizes, int n_in,
                              void* d_out, int out_size, void* d_ws, size_t ws_size,
                              hipStream_t stream) {
    const float* lf     = (const float*)d_in[0];
    const int*   eidx   = (const int*)d_in[1];
    const float* ef     = (const float*)d_in[2];
    const float* rf     = (const float*)d_in[3];
    const float* W_left = (const float*)d_in[4];
    const float* b_left = (const float*)d_in[5];
    const float* W_edge = (const float*)d_in[6];
    const float* W_right= (const float*)d_in[7];
    const float* W_final= (const float*)d_in[8];
    const float* b_final= (const float*)d_in[9];
    const float* W_post = (const float*)d_in[10];
    const float* b_post = (const float*)d_in[11];
    const float* W_out1 = (const float*)d_in[12];
    const float* b_out1 = (const float*)d_in[13];
    const float* W_out2 = (const float*)d_in[14];
    const float* b_out2 = (const float*)d_in[15];

    int n_left  = in_sizes[0] / EMB;
    int E       = in_sizes[2];
    int n_right = in_sizes[3] / EMB;
    float* out = (float*)d_out;

    int NB = (n_right + BNODES - 1) >> BSH;

    size_t need = (size_t)E * 8
                + ((size_t)n_left + (size_t)n_right) * 8 * 4   // Lpk, Rpk
                + (size_t)n_right * EMB * 4                    // S
                + (size_t)n_right * 4                          // deg
                + (size_t)(3 * MAXNB + 2) * 4;

    if (ws_size >= need && NB <= MAXNB) {
        u64* rec   = (u64*)d_ws;
        u32* Lpk   = (u32*)(rec + (size_t)E);
        u32* Rpk   = Lpk + (size_t)n_left * 8;
        float* S   = (float*)(Rpk + (size_t)n_right * 8);
        int* deg   = (int*)(S + (size_t)n_right * EMB);
        int* bhist = deg + n_right;
        int* boff  = bhist + MAXNB;      // NB+1 entries
        int* gcur  = boff + MAXNB + 1;

        zero_i32<<<(NB + 255) / 256, 256, 0, stream>>>(bhist, NB);
        linear16_pack_kernel<<<(n_left * 8 + 255) / 256, 256, 0, stream>>>(lf, W_left, b_left, Lpk, n_left);
        linear16_pack_kernel<<<(n_right * 8 + 255) / 256, 256, 0, stream>>>(rf, W_right, nullptr, Rpk, n_right);

        bucket_hist_kernel<<<512, 256, 0, stream>>>(eidx + E, bhist, E, NB);
        bucket_scan_kernel<<<1, 1024, 0, stream>>>(bhist, boff, gcur, NB);

        int nchunks = (E + PCHUNK - 1) / PCHUNK;
        partition_kernel<<<nchunks, 512, 0, stream>>>(eidx, ef, gcur, rec, E, NB);

        bucket_gather_kernel<<<NB, 512, 0, stream>>>(rec, boff, Lpk, Rpk, W_edge, S, deg, n_right);

        final_kernel<<<(n_right + 255) / 256, 256, 0, stream>>>(S, deg, rf,
            W_final, b_final, W_post, b_post, W_out1, b_out1, W_out2, b_out2, out, n_right);
    } else {
        float* L   = (float*)d_ws;
        float* R   = L + (size_t)n_left * EMB;
        float* S   = R + (size_t)n_right * EMB;
        int*   cnt = (int*)(S + (size_t)n_right * EMB);

        zero_f32<<<2048, 256, 0, stream>>>(S, (size_t)n_right * EMB);
        zero_i32<<<(n_right + 255) / 256, 256, 0, stream>>>(cnt, n_right);

        linear16_kernel<<<(n_left * EMB + 255) / 256, 256, 0, stream>>>(lf, W_left, b_left, L, n_left);
        linear16_kernel<<<(n_right * EMB + 255) / 256, 256, 0, stream>>>(rf, W_right, nullptr, R, n_right);

        long long ethreads = (long long)E * EMB;
        edge_kernel<<<(unsigned)((ethreads + 255) / 256), 256, 0, stream>>>(eidx, ef, L, R, W_edge, S, cnt, E);

        final_kernel<<<(n_right + 255) / 256, 256, 0, stream>>>(S, cnt, rf,
            W_final, b_final, W_post, b_post, W_out1, b_out1, W_out2, b_out2, out, n_right);
    }
}

// Round 8
// 131.135 us; speedup vs baseline: 3.3388x; 3.3388x over previous
//
#include <hip/hip_runtime.h>

#define EMB 16
#define BSH 7                 // 128 right-nodes per bucket
#define BNODES 128
#define MAXNB 1024
#define PCHUNK 16384
#define REC_CAP 5120          // records sorted per LDS tile (40 KB)
typedef unsigned int u32;
typedef unsigned long long u64;

__global__ void zero_f32(float* __restrict__ p, size_t n) {
    size_t i = (size_t)blockIdx.x * blockDim.x + threadIdx.x;
    size_t stride = (size_t)gridDim.x * blockDim.x;
    for (; i < n; i += stride) p[i] = 0.0f;
}

__global__ void zero_i32(int* __restrict__ p, int n) {
    int i = blockIdx.x * blockDim.x + threadIdx.x;
    if (i < n) p[i] = 0;
}

__device__ __forceinline__ u32 bf16bits_rne(float x) {
    u32 u = __float_as_uint(x);
    return (u + 0x7fffu + ((u >> 16) & 1u)) >> 16;
}

// Packed bf16 linear: Y[row*8+h] = pack(bf16(row@W[:,h+8]+b), bf16(row@W[:,h]+b))
__global__ void linear16_pack_kernel(const float* __restrict__ X, const float* __restrict__ W,
                                     const float* __restrict__ b, u32* __restrict__ Y, int N) {
    int tid = blockIdx.x * blockDim.x + threadIdx.x;
    int row = tid >> 3;
    int h = tid & 7;
    if (row >= N) return;
    float a0 = b ? b[h] : 0.0f;
    float a1 = b ? b[h + 8] : 0.0f;
    const float* xr = X + (size_t)row * EMB;
#pragma unroll
    for (int k = 0; k < EMB; ++k) {
        float xv = xr[k];
        a0 = fmaf(xv, W[k * EMB + h], a0);
        a1 = fmaf(xv, W[k * EMB + h + 8], a1);
    }
    Y[(size_t)row * 8 + h] = (bf16bits_rne(a1) << 16) | bf16bits_rne(a0);
}

// Plain f32 linear (fallback path)
__global__ void linear16_kernel(const float* __restrict__ X, const float* __restrict__ W,
                                const float* __restrict__ b, float* __restrict__ Y, int N) {
    int tid = blockIdx.x * blockDim.x + threadIdx.x;
    int row = tid >> 4;
    int j = tid & 15;
    if (row >= N) return;
    float acc = b ? b[j] : 0.0f;
    const float* xr = X + (size_t)row * EMB;
#pragma unroll
    for (int k = 0; k < EMB; ++k) acc = fmaf(xr[k], W[k * EMB + j], acc);
    Y[(size_t)row * EMB + j] = acc;
}

// ---------------- bucket CSR build ----------------

__global__ void bucket_hist_kernel(const int* __restrict__ ridx, int* __restrict__ bhist,
                                   int E, int NB) {
    __shared__ int h[MAXNB];
    int t = threadIdx.x;
    for (int i = t; i < NB; i += 256) h[i] = 0;
    __syncthreads();
    int idx = blockIdx.x * blockDim.x + t;
    int stride = gridDim.x * blockDim.x;
    for (int e = idx; e < E; e += stride) atomicAdd(&h[ridx[e] >> BSH], 1);
    __syncthreads();
    for (int i = t; i < NB; i += 256) if (h[i]) atomicAdd(&bhist[i], h[i]);
}

__global__ void bucket_scan_kernel(const int* __restrict__ bhist, int* __restrict__ boff,
                                   int* __restrict__ gcur, int NB) {
    __shared__ int sc[1024];
    int t = threadIdx.x;
    int v = (t < NB) ? bhist[t] : 0;
    sc[t] = v;
    __syncthreads();
    for (int d = 1; d < 1024; d <<= 1) {
        int x = (t >= d) ? sc[t - d] : 0;
        __syncthreads();
        sc[t] += x;
        __syncthreads();
    }
    int excl = sc[t] - v;
    if (t < NB) { boff[t] = excl; gcur[t] = excl; }
    if (t == 1023) boff[NB] = sc[1023];
}

// Two-pass partition: LDS hist -> one aggregated global reservation per bucket
// -> clustered scatter of packed records [f:32][l:24][rl:7].
__launch_bounds__(512)
__global__ void partition_kernel(const int* __restrict__ eidx, const float* __restrict__ ef,
                                 int* __restrict__ gcur, u64* __restrict__ rec, int E, int NB) {
    __shared__ int hist[MAXNB];
    __shared__ int lbase[MAXNB];
    int t = threadIdx.x;
    long long base = (long long)blockIdx.x * PCHUNK;
    int n = (int)((E - base) < PCHUNK ? (E - base) : PCHUNK);
    const int* ridx = eidx + E;
    for (int i = t; i < NB; i += 512) hist[i] = 0;
    __syncthreads();
    for (int i = t; i < n; i += 512) atomicAdd(&hist[ridx[base + i] >> BSH], 1);
    __syncthreads();
    for (int i = t; i < NB; i += 512) {
        int h = hist[i];
        lbase[i] = h ? atomicAdd(&gcur[i], h) : 0;
        hist[i] = 0;  // reuse as local cursor
    }
    __syncthreads();
    for (int i = t; i < n; i += 512) {
        int r = ridx[base + i];
        int b = r >> BSH;
        int l = eidx[base + i];
        float f = ef[base + i];
        int pos = lbase[b] + atomicAdd(&hist[b], 1);
        rec[pos] = ((u64)__float_as_uint(f) << 32) | ((u64)(u32)l << BSH) | (u32)(r & (BNODES - 1));
    }
}

// ---------------- gather: one block per 128-node bucket ----------------
// In-block counting sort by local node id (int LDS atomics only), then
// owner-computes: 4 threads per node accumulate in REGISTERS (zero fp atomics),
// combine via shfl_xor, coalesced float4 store of S.
__launch_bounds__(512)
__global__ void bucket_gather_kernel(const u64* __restrict__ rec, const int* __restrict__ boff,
                                     const u32* __restrict__ Lpk, const u32* __restrict__ Rpk,
                                     const float* __restrict__ We,
                                     float* __restrict__ S, int* __restrict__ deg, int n_right) {
    __shared__ u64 srec[REC_CAP];                        // 40 KB sorted records
    __shared__ int hist[BNODES], sc[BNODES], base_[BNODES], cur[BNODES];
    int b = blockIdx.x;
    int t = threadIdx.x;
    int node0 = b << BSH;
    int start = boff[b], end = boff[b + 1];

    int n = t >> 2, q = t & 3;        // owner: node n (0..127), slice q (0..3)
    int node = node0 + n;
    bool nv = node < n_right;

    float we[16];
#pragma unroll
    for (int j = 0; j < 16; ++j) we[j] = We[j];

    float rv[16];
    if (nv) {
        const uint4* rp = (const uint4*)(Rpk + (size_t)node * 8);
        uint4 ra = rp[0], rb = rp[1];
        u32 w0 = ra.x, w1 = ra.y, w2 = ra.z, w3 = ra.w;
        u32 w4 = rb.x, w5 = rb.y, w6 = rb.z, w7 = rb.w;
        rv[0] = __uint_as_float(w0 << 16); rv[8]  = __uint_as_float(w0 & 0xffff0000u);
        rv[1] = __uint_as_float(w1 << 16); rv[9]  = __uint_as_float(w1 & 0xffff0000u);
        rv[2] = __uint_as_float(w2 << 16); rv[10] = __uint_as_float(w2 & 0xffff0000u);
        rv[3] = __uint_as_float(w3 << 16); rv[11] = __uint_as_float(w3 & 0xffff0000u);
        rv[4] = __uint_as_float(w4 << 16); rv[12] = __uint_as_float(w4 & 0xffff0000u);
        rv[5] = __uint_as_float(w5 << 16); rv[13] = __uint_as_float(w5 & 0xffff0000u);
        rv[6] = __uint_as_float(w6 << 16); rv[14] = __uint_as_float(w6 & 0xffff0000u);
        rv[7] = __uint_as_float(w7 << 16); rv[15] = __uint_as_float(w7 & 0xffff0000u);
    } else {
#pragma unroll
        for (int j = 0; j < 16; ++j) rv[j] = 0.0f;
    }

    float acc[16];
#pragma unroll
    for (int j = 0; j < 16; ++j) acc[j] = 0.0f;
    int dsum = 0;

    for (int tile = start; tile < end; tile += REC_CAP) {
        int m = end - tile; if (m > REC_CAP) m = REC_CAP;
        for (int i = t; i < BNODES; i += 512) hist[i] = 0;
        __syncthreads();
        // pass 1: per-node count (int LDS atomics)
        for (int i = t; i < m; i += 512) {
            u64 rc = rec[tile + i];
            atomicAdd(&hist[(int)(rc & (u32)(BNODES - 1))], 1);
        }
        __syncthreads();
        // exclusive scan over 128 counts (Hillis-Steele, uniform barriers)
        if (t < BNODES) sc[t] = hist[t];
        __syncthreads();
        for (int d = 1; d < BNODES; d <<= 1) {
            int v = 0;
            if (t < BNODES && t >= d) v = sc[t - d];
            __syncthreads();
            if (t < BNODES && t >= d) sc[t] += v;
            __syncthreads();
        }
        if (t < BNODES) { int e0 = sc[t] - hist[t]; base_[t] = e0; cur[t] = e0; }
        __syncthreads();
        // pass 2: scatter records into sorted LDS positions (int LDS atomics)
        for (int i = t; i < m; i += 512) {
            u64 rc = rec[tile + i];
            int pos = atomicAdd(&cur[(int)(rc & (u32)(BNODES - 1))], 1);
            srec[pos] = rc;
        }
        __syncthreads();
        // owner phase: node n's slice-q thread walks its run, register accumulate
        {
            int c  = nv ? hist[n] : 0;
            int b0 = nv ? base_[n] : 0;
            if (q == 0) dsum += c;
            for (int k = q; k < c; k += 4) {
                u64 rc = srec[b0 + k];
                int l = (int)((rc >> BSH) & 0xFFFFFFu);
                float f = __uint_as_float((u32)(rc >> 32));
                const uint4* lp = (const uint4*)(Lpk + (size_t)l * 8);
                uint4 la = lp[0], lb = lp[1];
                u32 w0 = la.x, w1 = la.y, w2 = la.z, w3 = la.w;
                u32 w4 = lb.x, w5 = lb.y, w6 = lb.z, w7 = lb.w;
#define PAIR(h, lw) { \
                float l0 = __uint_as_float(lw << 16); \
                float l1 = __uint_as_float(lw & 0xffff0000u); \
                acc[h]     += fmaxf(fmaf(f, we[h], l0) + rv[h], 0.0f); \
                acc[h + 8] += fmaxf(fmaf(f, we[h + 8], l1) + rv[h + 8], 0.0f); }
                PAIR(0, w0) PAIR(1, w1) PAIR(2, w2) PAIR(3, w3)
                PAIR(4, w4) PAIR(5, w5) PAIR(6, w6) PAIR(7, w7)
#undef PAIR
            }
        }
        __syncthreads();  // before hist/srec reuse in next tile
    }

    // combine the 4 owner slices (lanes 4n..4n+3 are in the same wave)
#pragma unroll
    for (int j = 0; j < 16; ++j) {
        acc[j] += __shfl_xor(acc[j], 1, 64);
        acc[j] += __shfl_xor(acc[j], 2, 64);
    }
    if (nv) {
        float4 o = make_float4(acc[q * 4], acc[q * 4 + 1], acc[q * 4 + 2], acc[q * 4 + 3]);
        ((float4*)(S + (size_t)node * EMB))[q] = o;
        if (q == 0) deg[node] = dsum;
    }
}

// ---------------- fallback atomic edge kernel (f32 tables) ----------------
__global__ void edge_kernel(const int* __restrict__ eidx, const float* __restrict__ ef,
                            const float* __restrict__ L, const float* __restrict__ R,
                            const float* __restrict__ We, float* __restrict__ S,
                            int* __restrict__ cnt, int E) {
    long long tid = (long long)blockIdx.x * blockDim.x + threadIdx.x;
    int e = (int)(tid >> 4);
    int j = (int)(tid & 15);
    if (e >= E) return;
    int l = eidx[e];
    int r = eidx[E + e];
    float v = L[(size_t)l * EMB + j] + ef[e] * We[j] + R[(size_t)r * EMB + j];
    v = fmaxf(v, 0.0f);
    unsafeAtomicAdd(&S[(size_t)r * EMB + j], v);
    if (j == 0) atomicAdd(&cnt[r], 1);
}

// ---------------- per-node epilogue ----------------
__global__ void final_kernel(const float* __restrict__ S, const int* __restrict__ deg,
                             const float* __restrict__ rf,
                             const float* __restrict__ Wf, const float* __restrict__ bf,
                             const float* __restrict__ Wp, const float* __restrict__ bp,
                             const float* __restrict__ Wo1, const float* __restrict__ bo1,
                             const float* __restrict__ Wo2, const float* __restrict__ bo2,
                             float* __restrict__ out, int N) {
    __shared__ float sWf[256], sWp[256], sWo1[512], sWo2[256];
    __shared__ float sb[64];
    int t = threadIdx.x;
    for (int i = t; i < 256; i += 256) { sWf[i] = Wf[i]; sWp[i] = Wp[i]; sWo2[i] = Wo2[i]; }
    for (int i = t; i < 512; i += 256) sWo1[i] = Wo1[i];
    if (t < 16) { sb[t] = bf[t]; sb[16 + t] = bp[t]; sb[32 + t] = bo1[t]; sb[48 + t] = bo2[t]; }
    __syncthreads();

    int r = blockIdx.x * blockDim.x + t;
    if (r >= N) return;

    float s[16], x[16], y[16], rv[16], z[16], o[16];
    const float4* Sp = (const float4*)(S + (size_t)r * EMB);
    const float4* Rp = (const float4*)(rf + (size_t)r * EMB);
#pragma unroll
    for (int k = 0; k < 4; ++k) {
        float4 v = Sp[k];
        s[4 * k] = v.x; s[4 * k + 1] = v.y; s[4 * k + 2] = v.z; s[4 * k + 3] = v.w;
        float4 w = Rp[k];
        rv[4 * k] = w.x; rv[4 * k + 1] = w.y; rv[4 * k + 2] = w.z; rv[4 * k + 3] = w.w;
    }
    float c = (float)deg[r];

#pragma unroll
    for (int j = 0; j < 16; ++j) {
        float a = c * sb[j];
#pragma unroll
        for (int k = 0; k < 16; ++k) a = fmaf(s[k], sWf[k * 16 + j], a);
        x[j] = fmaxf(a, 0.0f);
    }
#pragma unroll
    for (int j = 0; j < 16; ++j) {
        float a = sb[16 + j];
#pragma unroll
        for (int k = 0; k < 16; ++k) a = fmaf(x[k], sWp[k * 16 + j], a);
        y[j] = a;
    }
#pragma unroll
    for (int j = 0; j < 16; ++j) {
        float a = sb[32 + j];
#pragma unroll
        for (int k = 0; k < 16; ++k) a = fmaf(y[k], sWo1[k * 16 + j], a);
#pragma unroll
        for (int k = 0; k < 16; ++k) a = fmaf(rv[k], sWo1[(16 + k) * 16 + j], a);
        z[j] = fmaxf(a, 0.0f);
    }
#pragma unroll
    for (int j = 0; j < 16; ++j) {
        float a = sb[48 + j];
#pragma unroll
        for (int k = 0; k < 16; ++k) a = fmaf(z[k], sWo2[k * 16 + j], a);
        o[j] = a;
    }
    float4* Op = (float4*)(out + (size_t)r * EMB);
#pragma unroll
    for (int k = 0; k < 4; ++k)
        Op[k] = make_float4(o[4 * k], o[4 * k + 1], o[4 * k + 2], o[4 * k + 3]);
}

extern "C" void kernel_launch(void* const* d_in, const int* in_sizes, int n_in,
                              void* d_out, int out_size, void* d_ws, size_t ws_size,
                              hipStream_t stream) {
    const float* lf     = (const float*)d_in[0];
    const int*   eidx   = (const int*)d_in[1];
    const float* ef     = (const float*)d_in[2];
    const float* rf     = (const float*)d_in[3];
    const float* W_left = (const float*)d_in[4];
    const float* b_left = (const float*)d_in[5];
    const float* W_edge = (const float*)d_in[6];
    const float* W_right= (const float*)d_in[7];
    const float* W_final= (const float*)d_in[8];
    const float* b_final= (const float*)d_in[9];
    const float* W_post = (const float*)d_in[10];
    const float* b_post = (const float*)d_in[11];
    const float* W_out1 = (const float*)d_in[12];
    const float* b_out1 = (const float*)d_in[13];
    const float* W_out2 = (const float*)d_in[14];
    const float* b_out2 = (const float*)d_in[15];

    int n_left  = in_sizes[0] / EMB;
    int E       = in_sizes[2];
    int n_right = in_sizes[3] / EMB;
    float* out = (float*)d_out;

    int NB = (n_right + BNODES - 1) >> BSH;

    size_t need = (size_t)E * 8
                + ((size_t)n_left + (size_t)n_right) * 8 * 4   // Lpk, Rpk
                + (size_t)n_right * EMB * 4                    // S
                + (size_t)n_right * 4                          // deg
                + (size_t)(3 * MAXNB + 2) * 4;

    if (ws_size >= need && NB <= MAXNB) {
        u64* rec   = (u64*)d_ws;
        u32* Lpk   = (u32*)(rec + (size_t)E);
        u32* Rpk   = Lpk + (size_t)n_left * 8;
        float* S   = (float*)(Rpk + (size_t)n_right * 8);
        int* deg   = (int*)(S + (size_t)n_right * EMB);
        int* bhist = deg + n_right;
        int* boff  = bhist + MAXNB;      // NB+1 entries
        int* gcur  = boff + MAXNB + 1;

        zero_i32<<<(NB + 255) / 256, 256, 0, stream>>>(bhist, NB);
        linear16_pack_kernel<<<(n_left * 8 + 255) / 256, 256, 0, stream>>>(lf, W_left, b_left, Lpk, n_left);
        linear16_pack_kernel<<<(n_right * 8 + 255) / 256, 256, 0, stream>>>(rf, W_right, nullptr, Rpk, n_right);

        bucket_hist_kernel<<<512, 256, 0, stream>>>(eidx + E, bhist, E, NB);
        bucket_scan_kernel<<<1, 1024, 0, stream>>>(bhist, boff, gcur, NB);

        int nchunks = (E + PCHUNK - 1) / PCHUNK;
        partition_kernel<<<nchunks, 512, 0, stream>>>(eidx, ef, gcur, rec, E, NB);

        bucket_gather_kernel<<<NB, 512, 0, stream>>>(rec, boff, Lpk, Rpk, W_edge, S, deg, n_right);

        final_kernel<<<(n_right + 255) / 256, 256, 0, stream>>>(S, deg, rf,
            W_final, b_final, W_post, b_post, W_out1, b_out1, W_out2, b_out2, out, n_right);
    } else {
        float* L   = (float*)d_ws;
        float* R   = L + (size_t)n_left * EMB;
        float* S   = R + (size_t)n_right * EMB;
        int*   cnt = (int*)(S + (size_t)n_right * EMB);

        zero_f32<<<2048, 256, 0, stream>>>(S, (size_t)n_right * EMB);
        zero_i32<<<(n_right + 255) / 256, 256, 0, stream>>>(cnt, n_right);

        linear16_kernel<<<(n_left * EMB + 255) / 256, 256, 0, stream>>>(lf, W_left, b_left, L, n_left);
        linear16_kernel<<<(n_right * EMB + 255) / 256, 256, 0, stream>>>(rf, W_right, nullptr, R, n_right);

        long long ethreads = (long long)E * EMB;
        edge_kernel<<<(unsigned)((ethreads + 255) / 256), 256, 0, stream>>>(eidx, ef, L, R, W_edge, S, cnt, E);

        final_kernel<<<(n_right + 255) / 256, 256, 0, stream>>>(S, cnt, rf,
            W_final, b_final, W_post, b_post, W_out1, b_out1, W_out2, b_out2, out, n_right);
    }
}